// Round 23
// baseline (150.580 us; speedup 1.0000x reference)
//
#include <hip/hip_runtime.h>
#include <float.h>

#define NTOK 32768  // 16 * 2048 tokens per modality

typedef __attribute__((ext_vector_type(8))) short bf16x8;
typedef __attribute__((ext_vector_type(4))) float f32x4;

// ---- ws byte layout ----
#define WSB_W2    0          // 1280 floats
#define WSB_X2    8192       // 5*NTOK floats
#define WSB_CNT   663808     // 5 ints
#define WSB_LIST  664064     // 5*NTOK ints
#define WSB_WSP   1572864    // dual-plane bf16 tile slabs (852 KB)

#define GLOAD16(g, l)                                                        \
  __builtin_amdgcn_global_load_lds(                                          \
      (__attribute__((address_space(1))) const void*)(const void*)(g),       \
      (__attribute__((address_space(3))) void*)(void*)(l), 16, 0, 0)

struct AllPtrs {
    const float* X[5];
    const float* W[5];
    unsigned char* Wsp[5];
    float* w2[5];
    float* q[5];
    float* idx[5];
    float* x2[5];
    int* cnt;
    int* lst;                  // + m*NTOK
    float* loss;
};

__device__ __forceinline__ unsigned short f2bf(float f) {
    unsigned u = __float_as_uint(f);
    return (unsigned short)((u + 0x7FFFu + ((u >> 16) & 1u)) >> 16);
}
__device__ __forceinline__ float bf2f(unsigned short h) {
    return __uint_as_float(((unsigned)h) << 16);
}

// ============ numpy pairwise-sum replica (fp32, PW_BLOCKSIZE=128) ===========
__device__ __forceinline__ float pw_sq_block_g(const float* __restrict__ a, int n) {
    float r[8];
    #pragma unroll
    for (int j = 0; j < 8; ++j) r[j] = __fmul_rn(a[j], a[j]);
    for (int i = 8; i < n; i += 8)
        #pragma unroll
        for (int j = 0; j < 8; ++j)
            r[j] = __fadd_rn(r[j], __fmul_rn(a[i + j], a[i + j]));
    return __fadd_rn(__fadd_rn(__fadd_rn(r[0], r[1]), __fadd_rn(r[2], r[3])),
                     __fadd_rn(__fadd_rn(r[4], r[5]), __fadd_rn(r[6], r[7])));
}

template <int D>
__device__ __forceinline__ void w2_body(const float* __restrict__ W,
                                        float* __restrict__ w2, int k, int K) {
    if (k >= K) return;
    const float* row = W + (size_t)k * D;
    float s = (D > 128)
        ? __fadd_rn(pw_sq_block_g(row, 128), pw_sq_block_g(row + 128, D - 128))
        : pw_sq_block_g(row, D);
    w2[k] = s;
}

// ---- pack W as per-tile dual-plane fragment slabs -------------------------
template <int D, int K>
__device__ __forceinline__ void wsplit_body(const float* __restrict__ W,
                                            unsigned char* __restrict__ dst, int i) {
    if (i >= K * D / 2) return;
    int k  = i / (D / 2);
    int d2 = i % (D / 2);
    int d  = 2 * d2;
    float2 v = *(const float2*)(W + (size_t)k * D + d);
    unsigned short h0 = f2bf(v.x), h1 = f2bf(v.y);
    unsigned short l0 = f2bf(__fsub_rn(v.x, bf2f(h0)));
    unsigned short l1 = f2bf(__fsub_rn(v.y, bf2f(h1)));
    int tile = k >> 4, row = k & 15;
    int ds = d >> 5, kg = (d >> 3) & 3, e = d & 7;
    int lane = row | (kg << 4);
    size_t base = (size_t)tile * (D * 64) + ds * 1024 + lane * 16 + e * 2;
    *(unsigned int*)(dst + base)          = (unsigned)h0 | ((unsigned)h1 << 16);
    *(unsigned int*)(dst + base + D * 32) = (unsigned)l0 | ((unsigned)l1 << 16);
}

// ---- prep: zero loss/cnt, w2 (np-replica), W packed planes ----------------
__global__ __launch_bounds__(256) void prep_mega(AllPtrs P) {
    const int bid = blockIdx.x, tid = threadIdx.x;
    if (bid == 0 && tid == 0) *P.loss = 0.f;
    if (bid == 0 && tid < 5) P.cnt[tid] = 0;
    if (bid < 6) {
        if (bid < 2)      w2_body<256>(P.W[0], P.w2[0], bid * 256 + tid, 512);
        else if (bid == 2) w2_body<128>(P.W[1], P.w2[1], tid, 256);
        else if (bid == 3) w2_body<64> (P.W[2], P.w2[2], tid, 128);
        else if (bid == 4) w2_body<128>(P.W[3], P.w2[3], tid, 256);
        else               w2_body<64> (P.W[4], P.w2[4], tid, 128);
    } else {
        int b = bid - 6;
        if (b < 256)      wsplit_body<256, 512>(P.W[0], P.Wsp[0], b * 256 + tid);
        else if (b < 320) wsplit_body<128, 256>(P.W[1], P.Wsp[1], (b - 256) * 256 + tid);
        else if (b < 336) wsplit_body<64, 128> (P.W[2], P.Wsp[2], (b - 320) * 256 + tid);
        else if (b < 400) wsplit_body<128, 256>(P.W[3], P.Wsp[3], (b - 336) * 256 + tid);
        else              wsplit_body<64, 128> (P.W[4], P.Wsp[4], (b - 400) * 256 + tid);
    }
}

// ---- numpy-pairwise ||x||^2 replica, wave-cooperative ----------------------
template <int D>
__device__ __forceinline__ float x2_replica(const float* __restrict__ xr, int lane) {
    const int jg = (lane >> 4) & 3;
    constexpr int B1M = (D > 128) ? 16 : (D / 8);
    float2 v = *(const float2*)(xr + 2 * jg);
    float r0 = __fmul_rn(v.x, v.x), r1 = __fmul_rn(v.y, v.y);
    #pragma unroll
    for (int m = 1; m < B1M; ++m) {
        float2 u = *(const float2*)(xr + 8 * m + 2 * jg);
        r0 = __fadd_rn(r0, __fmul_rn(u.x, u.x));
        r1 = __fadd_rn(r1, __fmul_rn(u.y, u.y));
    }
    float p = __fadd_rn(r0, r1);
    p = __fadd_rn(p, __shfl_xor(p, 16, 64));
    p = __fadd_rn(p, __shfl_xor(p, 32, 64));
    if (D > 128) {
        float2 w0 = *(const float2*)(xr + 128 + 2 * jg);
        float s0 = __fmul_rn(w0.x, w0.x), s1 = __fmul_rn(w0.y, w0.y);
        #pragma unroll
        for (int m = 1; m < 16; ++m) {
            float2 u = *(const float2*)(xr + 128 + 8 * m + 2 * jg);
            s0 = __fadd_rn(s0, __fmul_rn(u.x, u.x));
            s1 = __fadd_rn(s1, __fmul_rn(u.y, u.y));
        }
        float q2 = __fadd_rn(s0, s1);
        q2 = __fadd_rn(q2, __shfl_xor(q2, 16, 64));
        q2 = __fadd_rn(q2, __shfl_xor(q2, 32, 64));
        p = __fadd_rn(p, q2);
    }
    return p;
}

__device__ __forceinline__ void load_frags(const float* xr, bf16x8* bh, bf16x8* bl,
                                           int DSn) {
    for (int ds = 0; ds < DSn; ++ds) {
        float4 a = *(const float4*)(xr + ds * 32);
        float4 b = *(const float4*)(xr + ds * 32 + 4);
        float f[8] = {a.x, a.y, a.z, a.w, b.x, b.y, b.z, b.w};
        bf16x8 h, l;
        #pragma unroll
        for (int j = 0; j < 8; ++j) {
            unsigned short hh = f2bf(f[j]);
            h[j] = (short)hh;
            l[j] = (short)f2bf(__fsub_rn(f[j], bf2f(hh)));
        }
        bh[ds] = h; bl[ds] = l;
    }
}

// full-wave top-2 merge + flag + loss term (valid on lane>>4==0)
__device__ __forceinline__ float merge_flag(float b1v, float b2v, int b1i,
                                            float x2v, int tw, int tloc,
                                            int lane, int* idx_s, float* idx_out,
                                            int* cnt_m, int* lst_m) {
    float v1 = b1v, v2 = b2v; int i1 = b1i;
    #pragma unroll
    for (int m = 16; m < 64; m <<= 1) {
        float o1 = __shfl_xor(v1, m, 64);
        float o2 = __shfl_xor(v2, m, 64);
        int   oi = __shfl_xor(i1, m, 64);
        bool better = (o1 < v1) || (o1 == v1 && oi < i1);
        float nb2 = better ? fminf(v1, o2) : fminf(o1, v2);
        if (better) { v1 = o1; i1 = oi; }
        v2 = nb2;
    }
    float ls = 0.f;
    if ((lane >> 4) == 0) {
        idx_s[tloc] = i1;
        idx_out[tw] = (float)i1;
        ls = __fadd_rn(x2v, v1);
        float margin = fmaf(x2v, 2.6e-7f, 4e-6f);
        if (v2 - v1 <= margin) {
            int p = atomicAdd(cnt_m, 1);
            lst_m[p] = tw;
        }
    }
    return ls;
}

// ---- K-split hand body: 1024 thr (2 groups x 8 waves), 128 tok -------------
// Group g scores k in [g*K/2, (g+1)*K/2); per-stage: each group stages CH=2
// tiles (32KB total). Cross-half merge: half-0 wins ties (lower index).
template <int D, int K, int M>
__device__ void vq_body_ks(const AllPtrs& P, int bid, unsigned char* lds,
                           int* idx_s, float* lred, float (*mv1)[128],
                           float (*mv2)[128], int (*mi1)[128])
{
    constexpr int DS   = D / 32;          // 8
    constexpr int TS   = D * 64;          // 16KB tile slab
    constexpr int NTH  = K / 32;          // tiles per half = 16
    constexpr int CH   = 2;               // tiles per group per stage
    constexpr int NST  = NTH / CH;        // 8 stages
    const float inv_nd = 1.0f / (32768.0f * (float)D);

    const float* X   = P.X[M];
    const float* W   = P.W[M];
    const unsigned char* Wsp = P.Wsp[M];
    const float* w2  = P.w2[M];
    float* q_out     = P.q[M];
    float* idx_out   = P.idx[M];
    float* x2_save   = P.x2[M];
    int*   cnt_m     = P.cnt + M;
    int*   lst_m     = P.lst + M * NTOK;

    const int tid  = threadIdx.x;
    const int lane = tid & 63;
    const int wv   = tid >> 6;            // 0..15
    const int g    = wv >> 3;             // K-half group
    const int gtid = tid & 511;           // thread within group
    const int t0   = bid * 128;
    const int tloc = (wv & 7) * 16 + (lane & 15);
    const int tw   = t0 + tloc;

    // x2 (group 0 only computes/saves; used for merge+loss)
    float x2v = 0.f;
    if (g == 0) {
        x2v = x2_replica<D>(X + (size_t)tw * D, lane);
        if ((lane >> 4) == 0) x2_save[tw] = x2v;
    }

    bf16x8 bhi[DS], blo[DS];
    load_frags(X + (size_t)tw * D + ((lane >> 4) & 3) * 8, bhi, blo, DS);

    float b1v = FLT_MAX, b2v = FLT_MAX;
    int   b1i = 0;
    {
        const int g16 = lane >> 4;
        for (int st = 0; st < NST; ++st) {
            __syncthreads();
            // stage: group0 threads load low-half tiles, group1 high-half
            const size_t off = (size_t)((g ? NTH : 0) + st * CH) * TS;
            const unsigned char* src = Wsp + off;
            unsigned char* dl = lds + g * (CH * TS);
            #pragma unroll
            for (int s = 0; s < (CH * TS) / 8192; ++s)
                GLOAD16(src + gtid * 16 + s * 8192, dl + gtid * 16 + s * 8192);
            __syncthreads();
            #pragma unroll
            for (int j = 0; j < CH; ++j) {
                const unsigned char* base = lds + g * (CH * TS) + j * TS + lane * 16;
                f32x4 a0 = {0,0,0,0}, a1 = {0,0,0,0}, a2 = {0,0,0,0};
                #pragma unroll
                for (int ds = 0; ds < DS; ++ds) {
                    bf16x8 ahi = *(const bf16x8*)(base + ds * 1024);
                    bf16x8 alo = *(const bf16x8*)(base + D * 32 + ds * 1024);
                    a0 = __builtin_amdgcn_mfma_f32_16x16x32_bf16(ahi, bhi[ds], a0, 0, 0, 0);
                    a1 = __builtin_amdgcn_mfma_f32_16x16x32_bf16(ahi, blo[ds], a1, 0, 0, 0);
                    a2 = __builtin_amdgcn_mfma_f32_16x16x32_bf16(alo, bhi[ds], a2, 0, 0, 0);
                }
                const int kb = (g * NTH + st * CH + j) * 16 + g16 * 4;
                #pragma unroll
                for (int r = 0; r < 4; ++r) {          // k-ascending, strict <
                    float dot = __fadd_rn(__fadd_rn(a0[r], a1[r]), a2[r]);
                    float s = fmaf(-2.f, dot, w2[kb + r]);
                    if (s < b1v)      { b2v = b1v; b1v = s; b1i = kb + r; }
                    else if (s < b2v) { b2v = s; }
                }
            }
        }
    }

    // per-wave top-2 merge across 4 code subgroups; publish per half
    {
        float v1 = b1v, v2 = b2v; int i1 = b1i;
        #pragma unroll
        for (int m = 16; m < 64; m <<= 1) {
            float o1 = __shfl_xor(v1, m, 64);
            float o2 = __shfl_xor(v2, m, 64);
            int   oi = __shfl_xor(i1, m, 64);
            bool better = (o1 < v1) || (o1 == v1 && oi < i1);
            float nb2 = better ? fminf(v1, o2) : fminf(o1, v2);
            if (better) { v1 = o1; i1 = oi; }
            v2 = nb2;
        }
        if ((lane >> 4) == 0) {
            mv1[g][tloc] = v1; mi1[g][tloc] = i1; mv2[g][tloc] = v2;
        }
    }
    __syncthreads();

    // cross-half merge (half-0 wins ties = lower index), flag, loss
    float ls = 0.f;
    if (g == 0 && (lane >> 4) == 0) {
        float va = mv1[0][tloc], vb = mv1[1][tloc];
        int   ia = mi1[0][tloc], ib = mi1[1][tloc];
        float v1, v2; int i1;
        if (vb < va) { v1 = vb; i1 = ib; v2 = fminf(va, mv2[1][tloc]); }
        else         { v1 = va; i1 = ia; v2 = fminf(vb, mv2[0][tloc]); }
        idx_s[tloc] = i1;
        idx_out[tw] = (float)i1;
        ls = __fadd_rn(x2v, v1);
        float margin = fmaf(x2v, 2.6e-7f, 4e-6f);
        if (v2 - v1 <= margin) {
            int p = atomicAdd(cnt_m, 1);
            lst_m[p] = tw;
        }
    }
    #pragma unroll
    for (int off = 32; off > 0; off >>= 1) ls += __shfl_down(ls, off, 64);
    if (lane == 0) lred[wv] = ls;               // group1 writes 0
    __syncthreads();
    if (tid == 0) {
        float tot = 0.f;
        #pragma unroll
        for (int r = 0; r < 16; ++r) tot += lred[r];
        atomicAdd(P.loss, tot * inv_nd);
    }

    // gather q = W[idx]
    for (int i = tid; i < 128 * (D / 4); i += 1024) {
        int d4 = i % (D / 4);
        int t  = i / (D / 4);
        int k  = idx_s[t];
        const float4 w = *(const float4*)(W + (size_t)k * D + d4 * 4);
        *(float4*)(q_out + (size_t)(t0 + t) * D + d4 * 4) = w;
    }
}

// ---- 2-set body (D<=128): 1024 thr, 512 tok (R22-proven) -------------------
template <int D, int K, int CH, int M>
__device__ void vq_body2(const AllPtrs& P, int bid, unsigned char* lds,
                         int* idx_s, float* lred)
{
    constexpr int DS   = D / 32;
    constexpr int NST  = (K / 16) / CH;
    constexpr int SB   = CH * D * 64;
    constexpr int ITER = SB / 16384;
    const float inv_nd = 1.0f / (32768.0f * (float)D);

    const float* X   = P.X[M];
    const float* W   = P.W[M];
    const unsigned char* Wsp = P.Wsp[M];
    const float* w2  = P.w2[M];
    float* q_out     = P.q[M];
    float* idx_out   = P.idx[M];
    float* x2_save   = P.x2[M];
    int*   cnt_m     = P.cnt + M;
    int*   lst_m     = P.lst + M * NTOK;

    const int tid  = threadIdx.x;
    const int lane = tid & 63;
    const int wv   = tid >> 6;
    const int t0   = bid * 512;
    const int tl0  = wv * 16 + (lane & 15);
    const int tw0  = t0 + tl0;
    const int tw1  = tw0 + 256;

    const float x2v0 = x2_replica<D>(X + (size_t)tw0 * D, lane);
    const float x2v1 = x2_replica<D>(X + (size_t)tw1 * D, lane);
    if ((lane >> 4) == 0) { x2_save[tw0] = x2v0; x2_save[tw1] = x2v1; }

    bf16x8 bhi0[DS], blo0[DS], bhi1[DS], blo1[DS];
    load_frags(X + (size_t)tw0 * D + ((lane >> 4) & 3) * 8, bhi0, blo0, DS);
    load_frags(X + (size_t)tw1 * D + ((lane >> 4) & 3) * 8, bhi1, blo1, DS);

    float b1v0 = FLT_MAX, b2v0 = FLT_MAX, b1v1 = FLT_MAX, b2v1 = FLT_MAX;
    int   b1i0 = 0, b1i1 = 0;
    {
        const int g = lane >> 4;
        for (int st = 0; st < NST; ++st) {
            __syncthreads();
            const unsigned char* src = Wsp + (size_t)st * SB;
            #pragma unroll
            for (int s = 0; s < ITER; ++s)
                GLOAD16(src + tid * 16 + s * 16384, lds + tid * 16 + s * 16384);
            __syncthreads();
            #pragma unroll
            for (int j = 0; j < CH; ++j) {
                const unsigned char* base = lds + j * (D * 64) + lane * 16;
                f32x4 p0 = {0,0,0,0}, p1 = {0,0,0,0}, p2 = {0,0,0,0};
                f32x4 q0 = {0,0,0,0}, q1 = {0,0,0,0}, q2 = {0,0,0,0};
                #pragma unroll
                for (int ds = 0; ds < DS; ++ds) {
                    bf16x8 ahi = *(const bf16x8*)(base + ds * 1024);
                    bf16x8 alo = *(const bf16x8*)(base + D * 32 + ds * 1024);
                    p0 = __builtin_amdgcn_mfma_f32_16x16x32_bf16(ahi, bhi0[ds], p0, 0, 0, 0);
                    q0 = __builtin_amdgcn_mfma_f32_16x16x32_bf16(ahi, bhi1[ds], q0, 0, 0, 0);
                    p1 = __builtin_amdgcn_mfma_f32_16x16x32_bf16(ahi, blo0[ds], p1, 0, 0, 0);
                    q1 = __builtin_amdgcn_mfma_f32_16x16x32_bf16(ahi, blo1[ds], q1, 0, 0, 0);
                    p2 = __builtin_amdgcn_mfma_f32_16x16x32_bf16(alo, bhi0[ds], p2, 0, 0, 0);
                    q2 = __builtin_amdgcn_mfma_f32_16x16x32_bf16(alo, bhi1[ds], q2, 0, 0, 0);
                }
                const int kb = (st * CH + j) * 16 + g * 4;
                #pragma unroll
                for (int r = 0; r < 4; ++r) {
                    float w2r = w2[kb + r];
                    float d0 = __fadd_rn(__fadd_rn(p0[r], p1[r]), p2[r]);
                    float s0 = fmaf(-2.f, d0, w2r);
                    if (s0 < b1v0)      { b2v0 = b1v0; b1v0 = s0; b1i0 = kb + r; }
                    else if (s0 < b2v0) { b2v0 = s0; }
                    float d1 = __fadd_rn(__fadd_rn(q0[r], q1[r]), q2[r]);
                    float s1 = fmaf(-2.f, d1, w2r);
                    if (s1 < b1v1)      { b2v1 = b1v1; b1v1 = s1; b1i1 = kb + r; }
                    else if (s1 < b2v1) { b2v1 = s1; }
                }
            }
        }
    }

    float ls = merge_flag(b1v0, b2v0, b1i0, x2v0, tw0, tl0, lane,
                          idx_s, idx_out, cnt_m, lst_m)
             + merge_flag(b1v1, b2v1, b1i1, x2v1, tw1, tl0 + 256, lane,
                          idx_s, idx_out, cnt_m, lst_m);
    #pragma unroll
    for (int off = 32; off > 0; off >>= 1) ls += __shfl_down(ls, off, 64);
    if (lane == 0) lred[wv] = ls;
    __syncthreads();
    if (tid == 0) {
        float tot = 0.f;
        #pragma unroll
        for (int r = 0; r < 16; ++r) tot += lred[r];
        atomicAdd(P.loss, tot * inv_nd);
    }

    for (int i = tid; i < 512 * (D / 4); i += 1024) {
        int d4 = i % (D / 4);
        int t  = i / (D / 4);
        int k  = idx_s[t];
        const float4 w = *(const float4*)(W + (size_t)k * D + d4 * 4);
        *(float4*)(q_out + (size_t)(t0 + t) * D + d4 * 4) = w;
    }
}

__global__ __launch_bounds__(1024) void vq_mega(AllPtrs P) {
    __shared__ __align__(16) unsigned char lds[65536];
    __shared__ int   idx_s[512];
    __shared__ float lred[16];
    __shared__ float mv1[2][128], mv2[2][128];
    __shared__ int   mi1[2][128];
    const int bid = blockIdx.x;
    if (bid < 256)       vq_body_ks<256, 512, 0>(P, bid, lds, idx_s, lred, mv1, mv2, mi1);
    else if (bid < 320)  vq_body2<128, 256, 8, 1>(P, bid - 256, lds, idx_s, lred);
    else if (bid < 384)  vq_body2<128, 256, 8, 3>(P, bid - 320, lds, idx_s, lred);
    else if (bid < 448)  vq_body2<64,  128, 8, 2>(P, bid - 384, lds, idx_s, lred);
    else                 vq_body2<64,  128, 8, 4>(P, bid - 448, lds, idx_s, lred);
}

// ---- unified cleanup: f32 prescan -> tiny f64 np-replica rescore -> patch --
template <int D, int K, int M>
__device__ void cleanup_body(const AllPtrs& P, int sbid, int sblk,
                             float* s32s, int* cand, float* rdv, int* rdi,
                             int* sh, float* wmin)
{
    constexpr int EPL = D / 16;
    const float* X  = P.X[M];
    const float* W  = P.W[M];
    const float* w2 = P.w2[M];
    const float* x2 = P.x2[M];
    const int* list = P.lst + M * NTOK;
    float* q_out   = P.q[M];
    float* idx_out = P.idx[M];
    const float inv_nd = 1.0f / (32768.0f * (float)D);
    const int n   = P.cnt[M];
    const int tid = threadIdx.x;
    const int cg  = tid >> 4;
    const int sub = tid & 15;

    for (int e = sbid; e < n; e += sblk) {
        __syncthreads();
        const int t = list[e];
        const float x2t = x2[t];
        const float* xp = X + (size_t)t * D + sub * EPL;
        float xr[EPL];
        for (int j = 0; j < EPL / 4; ++j) {
            float4 v = *(const float4*)(xp + j * 4);
            xr[j * 4 + 0] = v.x; xr[j * 4 + 1] = v.y;
            xr[j * 4 + 2] = v.z; xr[j * 4 + 3] = v.w;
        }
        if (tid == 0) sh[0] = 0;
        for (int it = 0; it < K / 16; ++it) {
            const int k = it * 16 + cg;
            const float* wp = W + (size_t)k * D + sub * EPL;
            float a = 0.f;
            for (int j = 0; j < EPL / 4; ++j) {
                float4 wv = *(const float4*)(wp + j * 4);
                a = fmaf(xr[j * 4 + 0], wv.x, a);
                a = fmaf(xr[j * 4 + 1], wv.y, a);
                a = fmaf(xr[j * 4 + 2], wv.z, a);
                a = fmaf(xr[j * 4 + 3], wv.w, a);
            }
            a += __shfl_down(a, 8, 16);
            a += __shfl_down(a, 4, 16);
            a += __shfl_down(a, 2, 16);
            a += __shfl_down(a, 1, 16);
            if (sub == 0) s32s[k] = fmaf(-2.f, a, w2[k]);
        }
        __syncthreads();
        float lm = FLT_MAX;
        for (int k = tid; k < K; k += 256) lm = fminf(lm, s32s[k]);
        #pragma unroll
        for (int off = 32; off; off >>= 1) lm = fminf(lm, __shfl_down(lm, off, 64));
        if ((tid & 63) == 0) wmin[tid >> 6] = lm;
        __syncthreads();
        const float m32 = fminf(fminf(wmin[0], wmin[1]), fminf(wmin[2], wmin[3]));
        const float win = fmaf(x2t, 2.6e-7f, 6e-6f);
        for (int k = tid; k < K; k += 256)
            if (s32s[k] <= m32 + win) {
                int p = atomicAdd(&sh[0], 1);
                if (p < 64) cand[p] = k;
            }
        __syncthreads();
        const int nc = sh[0];
        float bd = FLT_MAX; int bk = 0x7fffffff;
        for (int ci = cg; ci < ((nc <= 64) ? nc : K); ci += 16) {
            const int k = (nc <= 64) ? cand[ci] : ci;
            const float* wp = W + (size_t)k * D + sub * EPL;
            double a = 0.0;
            for (int j = 0; j < EPL; ++j)
                a = fma((double)xr[j], (double)wp[j], a);
            a += __shfl_down(a, 8, 16);
            a += __shfl_down(a, 4, 16);
            a += __shfl_down(a, 2, 16);
            a += __shfl_down(a, 1, 16);
            if (sub == 0) {
                const float m = (float)a;
                const float d = __fsub_rn(__fadd_rn(x2t, w2[k]),
                                          __fmul_rn(2.0f, m));
                if (d < bd || (d == bd && k < bk)) { bd = d; bk = k; }
            }
        }
        if (sub == 0) { rdv[cg] = bd; rdi[cg] = bk; }
        __syncthreads();
        if (tid == 0) {
            float B = rdv[0]; int BI = rdi[0];
            #pragma unroll
            for (int r = 1; r < 16; ++r)
                if (rdv[r] < B || (rdv[r] == B && rdi[r] < BI)) { B = rdv[r]; BI = rdi[r]; }
            const int oldk = (int)idx_out[t];
            sh[1] = BI; sh[2] = oldk;
            if (BI != oldk) idx_out[t] = (float)BI;
        }
        __syncthreads();
        const int nk = sh[1], ok = sh[2];
        if (nk != ok) {
            const float* xq = X + (size_t)t * D;
            const float* wn = W + (size_t)nk * D;
            const float* wo = W + (size_t)ok * D;
            float dl = 0.f;
            for (int d = tid; d < D; d += 256) {
                float xv = xq[d], a = wn[d], b = wo[d];
                q_out[(size_t)t * D + d] = a;
                float da = a - xv, db = b - xv;
                dl = fmaf(da, da, dl);
                dl = fmaf(-db, db, dl);
            }
            #pragma unroll
            for (int off = 32; off; off >>= 1) dl += __shfl_down(dl, off, 64);
            if ((tid & 63) == 0 && dl != 0.f) atomicAdd(P.loss, dl * inv_nd);
        }
    }
}

__global__ __launch_bounds__(256) void cleanup_mega(AllPtrs P) {
    __shared__ float s32s[512];
    __shared__ int   cand[64];
    __shared__ float rdv[16];
    __shared__ int   rdi[16];
    __shared__ int   sh[4];
    __shared__ float wmin[4];
    const int bid = blockIdx.x;
    if (bid < 256)       cleanup_body<256, 512, 0>(P, bid,        256, s32s, cand, rdv, rdi, sh, wmin);
    else if (bid < 512)  cleanup_body<128, 256, 1>(P, bid - 256,  256, s32s, cand, rdv, rdi, sh, wmin);
    else if (bid < 768)  cleanup_body<128, 256, 3>(P, bid - 512,  256, s32s, cand, rdv, rdi, sh, wmin);
    else if (bid < 1024) cleanup_body<64,  128, 2>(P, bid - 768,  256, s32s, cand, rdv, rdi, sh, wmin);
    else                 cleanup_body<64,  128, 4>(P, bid - 1024, 256, s32s, cand, rdv, rdi, sh, wmin);
}

extern "C" void kernel_launch(void* const* d_in, const int* in_sizes, int n_in,
                              void* d_out, int out_size, void* d_ws, size_t ws_size,
                              hipStream_t stream)
{
    float* out = (float*)d_out;
    unsigned char* wsb = (unsigned char*)d_ws;
    float* w2b = (float*)(wsb + WSB_W2);

    AllPtrs P;
    P.X[0] = (const float*)d_in[0]; P.W[0] = (const float*)d_in[1];
    P.X[1] = (const float*)d_in[2]; P.W[1] = (const float*)d_in[3];
    P.X[2] = (const float*)d_in[4]; P.W[2] = (const float*)d_in[5];
    P.X[3] = (const float*)d_in[6]; P.W[3] = (const float*)d_in[7];
    P.X[4] = (const float*)d_in[8]; P.W[4] = (const float*)d_in[9];

    P.q[0] = out;            P.q[1] = out + 8388608;  P.q[2] = out + 12582912;
    P.q[3] = out + 14680064; P.q[4] = out + 18874368;
    P.idx[0] = out + 20971520; P.idx[1] = out + 21004288;
    P.idx[2] = out + 21037056; P.idx[3] = out + 21069824;
    P.idx[4] = out + 21102592;
    P.loss = out + 21135360;

    P.w2[0] = w2b;       P.w2[1] = w2b + 512; P.w2[2] = w2b + 768;
    P.w2[3] = w2b + 896; P.w2[4] = w2b + 1152;
    float* x2b = (float*)(wsb + WSB_X2);
    for (int m = 0; m < 5; ++m) P.x2[m] = x2b + m * NTOK;
    P.cnt  = (int*)(wsb + WSB_CNT);
    P.lst  = (int*)(wsb + WSB_LIST);
    P.Wsp[0] = wsb + WSB_WSP;            // dual-plane: 4*K*D bytes each
    P.Wsp[1] = P.Wsp[0] + 524288;        // 131072
    P.Wsp[2] = P.Wsp[1] + 131072;        // 32768
    P.Wsp[3] = P.Wsp[2] + 32768;         // 131072
    P.Wsp[4] = P.Wsp[3] + 131072;        // 32768

    prep_mega   <<<422,  256,  0, stream>>>(P);
    vq_mega     <<<512,  1024, 0, stream>>>(P);
    cleanup_mega<<<1280, 256,  0, stream>>>(P);
}

// Round 24
// 127.510 us; speedup vs baseline: 1.1809x; 1.1809x over previous
//
#include <hip/hip_runtime.h>
#include <float.h>

#define NTOK 32768  // 16 * 2048 tokens per modality

typedef __attribute__((ext_vector_type(8))) short bf16x8;
typedef __attribute__((ext_vector_type(4))) float f32x4;

// ---- ws byte layout ----
#define WSB_W2    0          // 1280 floats
#define WSB_X2    8192       // 5*NTOK floats
#define WSB_CNT   663808     // 5 ints
#define WSB_LIST  664064     // 5*NTOK ints
#define WSB_WSP   1572864    // dual-plane bf16 tile slabs (852 KB)

#define GLOAD16(g, l)                                                        \
  __builtin_amdgcn_global_load_lds(                                          \
      (__attribute__((address_space(1))) const void*)(const void*)(g),       \
      (__attribute__((address_space(3))) void*)(void*)(l), 16, 0, 0)

struct AllPtrs {
    const float* X[5];
    const float* W[5];
    unsigned char* Wsp[5];
    float* w2[5];
    float* q[5];
    float* idx[5];
    float* x2[5];
    int* cnt;
    int* lst;                  // + m*NTOK
    float* loss;
};

__device__ __forceinline__ unsigned short f2bf(float f) {
    unsigned u = __float_as_uint(f);
    return (unsigned short)((u + 0x7FFFu + ((u >> 16) & 1u)) >> 16);
}
__device__ __forceinline__ float bf2f(unsigned short h) {
    return __uint_as_float(((unsigned)h) << 16);
}

// ============ numpy pairwise-sum replica (fp32, PW_BLOCKSIZE=128) ===========
__device__ __forceinline__ float pw_sq_block_g(const float* __restrict__ a, int n) {
    float r[8];
    #pragma unroll
    for (int j = 0; j < 8; ++j) r[j] = __fmul_rn(a[j], a[j]);
    for (int i = 8; i < n; i += 8)
        #pragma unroll
        for (int j = 0; j < 8; ++j)
            r[j] = __fadd_rn(r[j], __fmul_rn(a[i + j], a[i + j]));
    return __fadd_rn(__fadd_rn(__fadd_rn(r[0], r[1]), __fadd_rn(r[2], r[3])),
                     __fadd_rn(__fadd_rn(r[4], r[5]), __fadd_rn(r[6], r[7])));
}

template <int D>
__device__ __forceinline__ void w2_body(const float* __restrict__ W,
                                        float* __restrict__ w2, int k, int K) {
    if (k >= K) return;
    const float* row = W + (size_t)k * D;
    float s = (D > 128)
        ? __fadd_rn(pw_sq_block_g(row, 128), pw_sq_block_g(row + 128, D - 128))
        : pw_sq_block_g(row, D);
    w2[k] = s;
}

// ---- pack W as per-tile dual-plane fragment slabs -------------------------
template <int D, int K>
__device__ __forceinline__ void wsplit_body(const float* __restrict__ W,
                                            unsigned char* __restrict__ dst, int i) {
    if (i >= K * D / 2) return;
    int k  = i / (D / 2);
    int d2 = i % (D / 2);
    int d  = 2 * d2;
    float2 v = *(const float2*)(W + (size_t)k * D + d);
    unsigned short h0 = f2bf(v.x), h1 = f2bf(v.y);
    unsigned short l0 = f2bf(__fsub_rn(v.x, bf2f(h0)));
    unsigned short l1 = f2bf(__fsub_rn(v.y, bf2f(h1)));
    int tile = k >> 4, row = k & 15;
    int ds = d >> 5, kg = (d >> 3) & 3, e = d & 7;
    int lane = row | (kg << 4);
    size_t base = (size_t)tile * (D * 64) + ds * 1024 + lane * 16 + e * 2;
    *(unsigned int*)(dst + base)          = (unsigned)h0 | ((unsigned)h1 << 16);
    *(unsigned int*)(dst + base + D * 32) = (unsigned)l0 | ((unsigned)l1 << 16);
}

// ---- prep: zero loss/cnt, w2 (np-replica), W packed planes ----------------
__global__ __launch_bounds__(256) void prep_mega(AllPtrs P) {
    const int bid = blockIdx.x, tid = threadIdx.x;
    if (bid == 0 && tid == 0) *P.loss = 0.f;
    if (bid == 0 && tid < 5) P.cnt[tid] = 0;
    if (bid < 6) {
        if (bid < 2)      w2_body<256>(P.W[0], P.w2[0], bid * 256 + tid, 512);
        else if (bid == 2) w2_body<128>(P.W[1], P.w2[1], tid, 256);
        else if (bid == 3) w2_body<64> (P.W[2], P.w2[2], tid, 128);
        else if (bid == 4) w2_body<128>(P.W[3], P.w2[3], tid, 256);
        else               w2_body<64> (P.W[4], P.w2[4], tid, 128);
    } else {
        int b = bid - 6;
        if (b < 256)      wsplit_body<256, 512>(P.W[0], P.Wsp[0], b * 256 + tid);
        else if (b < 320) wsplit_body<128, 256>(P.W[1], P.Wsp[1], (b - 256) * 256 + tid);
        else if (b < 336) wsplit_body<64, 128> (P.W[2], P.Wsp[2], (b - 320) * 256 + tid);
        else if (b < 400) wsplit_body<128, 256>(P.W[3], P.Wsp[3], (b - 336) * 256 + tid);
        else              wsplit_body<64, 128> (P.W[4], P.Wsp[4], (b - 400) * 256 + tid);
    }
}

// ---- numpy-pairwise ||x||^2 replica, wave-cooperative ----------------------
template <int D>
__device__ __forceinline__ float x2_replica(const float* __restrict__ xr, int lane) {
    const int jg = (lane >> 4) & 3;
    constexpr int B1M = (D > 128) ? 16 : (D / 8);
    float2 v = *(const float2*)(xr + 2 * jg);
    float r0 = __fmul_rn(v.x, v.x), r1 = __fmul_rn(v.y, v.y);
    #pragma unroll
    for (int m = 1; m < B1M; ++m) {
        float2 u = *(const float2*)(xr + 8 * m + 2 * jg);
        r0 = __fadd_rn(r0, __fmul_rn(u.x, u.x));
        r1 = __fadd_rn(r1, __fmul_rn(u.y, u.y));
    }
    float p = __fadd_rn(r0, r1);
    p = __fadd_rn(p, __shfl_xor(p, 16, 64));
    p = __fadd_rn(p, __shfl_xor(p, 32, 64));
    if (D > 128) {
        float2 w0 = *(const float2*)(xr + 128 + 2 * jg);
        float s0 = __fmul_rn(w0.x, w0.x), s1 = __fmul_rn(w0.y, w0.y);
        #pragma unroll
        for (int m = 1; m < 16; ++m) {
            float2 u = *(const float2*)(xr + 128 + 8 * m + 2 * jg);
            s0 = __fadd_rn(s0, __fmul_rn(u.x, u.x));
            s1 = __fadd_rn(s1, __fmul_rn(u.y, u.y));
        }
        float q2 = __fadd_rn(s0, s1);
        q2 = __fadd_rn(q2, __shfl_xor(q2, 16, 64));
        q2 = __fadd_rn(q2, __shfl_xor(q2, 32, 64));
        p = __fadd_rn(p, q2);
    }
    return p;
}

__device__ __forceinline__ void load_frags(const float* xr, bf16x8* bh, bf16x8* bl,
                                           int DSn) {
    for (int ds = 0; ds < DSn; ++ds) {
        float4 a = *(const float4*)(xr + ds * 32);
        float4 b = *(const float4*)(xr + ds * 32 + 4);
        float f[8] = {a.x, a.y, a.z, a.w, b.x, b.y, b.z, b.w};
        bf16x8 h, l;
        #pragma unroll
        for (int j = 0; j < 8; ++j) {
            unsigned short hh = f2bf(f[j]);
            h[j] = (short)hh;
            l[j] = (short)f2bf(__fsub_rn(f[j], bf2f(hh)));
        }
        bh[ds] = h; bl[ds] = l;
    }
}

// top-2 wave merge + flag + return loss term (lane>>4==0 lanes only valid)
__device__ __forceinline__ float merge_flag(float b1v, float b2v, int b1i,
                                            float x2v, int tw, int tloc,
                                            int lane, int* idx_s, float* idx_out,
                                            int* cnt_m, int* lst_m) {
    float v1 = b1v, v2 = b2v; int i1 = b1i;
    #pragma unroll
    for (int m = 16; m < 64; m <<= 1) {
        float o1 = __shfl_xor(v1, m, 64);
        float o2 = __shfl_xor(v2, m, 64);
        int   oi = __shfl_xor(i1, m, 64);
        bool better = (o1 < v1) || (o1 == v1 && oi < i1);
        float nb2 = better ? fminf(v1, o2) : fminf(o1, v2);
        if (better) { v1 = o1; i1 = oi; }
        v2 = nb2;
    }
    float ls = 0.f;
    if ((lane >> 4) == 0) {
        idx_s[tloc] = i1;
        idx_out[tw] = (float)i1;
        ls = __fadd_rn(x2v, v1);
        float margin = fmaf(x2v, 2.6e-7f, 4e-6f);
        if (v2 - v1 <= margin) {
            int p = atomicAdd(cnt_m, 1);
            lst_m[p] = tw;
        }
    }
    return ls;
}

// ---- 1-set body (hand): 1024 thr (16 waves), 256 tok, 64KB superstages -----
template <int D, int K, int CH, int M>
__device__ void vq_body(const AllPtrs& P, int bid, unsigned char* lds,
                        int* idx_s, float* lred)
{
    constexpr int DS   = D / 32;
    constexpr int NST  = (K / 16) / CH;
    constexpr int SB   = CH * D * 64;
    constexpr int ITER = SB / 16384;      // GLOAD16 rounds (1024 thr)
    const float inv_nd = 1.0f / (32768.0f * (float)D);

    const float* X   = P.X[M];
    const float* W   = P.W[M];
    const unsigned char* Wsp = P.Wsp[M];
    const float* w2  = P.w2[M];
    float* q_out     = P.q[M];
    float* idx_out   = P.idx[M];
    float* x2_save   = P.x2[M];
    int*   cnt_m     = P.cnt + M;
    int*   lst_m     = P.lst + M * NTOK;

    const int tid  = threadIdx.x;
    const int lane = tid & 63;
    const int wv   = tid >> 6;            // 0..15
    const int t0   = bid * 256;
    const int tw   = t0 + wv * 16 + (lane & 15);

    const float x2v = x2_replica<D>(X + (size_t)tw * D, lane);
    if ((lane >> 4) == 0) x2_save[tw] = x2v;

    bf16x8 bhi[DS], blo[DS];
    load_frags(X + (size_t)tw * D + ((lane >> 4) & 3) * 8, bhi, blo, DS);

    float b1v = FLT_MAX, b2v = FLT_MAX;
    int   b1i = 0;
    {
        const int g = lane >> 4;
        for (int st = 0; st < NST; ++st) {
            __syncthreads();
            const unsigned char* src = Wsp + (size_t)st * SB;
            #pragma unroll
            for (int s = 0; s < ITER; ++s)
                GLOAD16(src + tid * 16 + s * 16384, lds + tid * 16 + s * 16384);
            __syncthreads();
            #pragma unroll
            for (int j = 0; j < CH; ++j) {
                const unsigned char* base = lds + j * (D * 64) + lane * 16;
                f32x4 a0 = {0,0,0,0}, a1 = {0,0,0,0}, a2 = {0,0,0,0};
                #pragma unroll
                for (int ds = 0; ds < DS; ++ds) {
                    bf16x8 ahi = *(const bf16x8*)(base + ds * 1024);
                    bf16x8 alo = *(const bf16x8*)(base + D * 32 + ds * 1024);
                    a0 = __builtin_amdgcn_mfma_f32_16x16x32_bf16(ahi, bhi[ds], a0, 0, 0, 0);
                    a1 = __builtin_amdgcn_mfma_f32_16x16x32_bf16(ahi, blo[ds], a1, 0, 0, 0);
                    a2 = __builtin_amdgcn_mfma_f32_16x16x32_bf16(alo, bhi[ds], a2, 0, 0, 0);
                }
                const int kb = (st * CH + j) * 16 + g * 4;
                #pragma unroll
                for (int r = 0; r < 4; ++r) {
                    float dot = __fadd_rn(__fadd_rn(a0[r], a1[r]), a2[r]);
                    float s = fmaf(-2.f, dot, w2[kb + r]);
                    if (s < b1v)      { b2v = b1v; b1v = s; b1i = kb + r; }
                    else if (s < b2v) { b2v = s; }
                }
            }
        }
    }

    float ls = merge_flag(b1v, b2v, b1i, x2v, tw, tw - t0, lane,
                          idx_s, idx_out, cnt_m, lst_m);
    #pragma unroll
    for (int off = 32; off > 0; off >>= 1) ls += __shfl_down(ls, off, 64);
    if (lane == 0) lred[wv] = ls;
    __syncthreads();
    if (tid == 0) {
        float tot = 0.f;
        #pragma unroll
        for (int r = 0; r < 16; ++r) tot += lred[r];
        atomicAdd(P.loss, tot * inv_nd);
    }

    for (int i = tid; i < 256 * (D / 4); i += 1024) {
        int d4 = i % (D / 4);
        int t  = i / (D / 4);
        int k  = idx_s[t];
        const float4 w = *(const float4*)(W + (size_t)k * D + d4 * 4);
        *(float4*)(q_out + (size_t)(t0 + t) * D + d4 * 4) = w;
    }
}

// ---- 2-set body (D<=128): 1024 thr, 512 tok, each W read feeds 6 MFMAs -----
template <int D, int K, int CH, int M>
__device__ void vq_body2(const AllPtrs& P, int bid, unsigned char* lds,
                         int* idx_s, float* lred)
{
    constexpr int DS   = D / 32;          // 4 or 2
    constexpr int NST  = (K / 16) / CH;
    constexpr int SB   = CH * D * 64;
    constexpr int ITER = SB / 16384;
    const float inv_nd = 1.0f / (32768.0f * (float)D);

    const float* X   = P.X[M];
    const float* W   = P.W[M];
    const unsigned char* Wsp = P.Wsp[M];
    const float* w2  = P.w2[M];
    float* q_out     = P.q[M];
    float* idx_out   = P.idx[M];
    float* x2_save   = P.x2[M];
    int*   cnt_m     = P.cnt + M;
    int*   lst_m     = P.lst + M * NTOK;

    const int tid  = threadIdx.x;
    const int lane = tid & 63;
    const int wv   = tid >> 6;            // 0..15
    const int t0   = bid * 512;
    const int tl0  = wv * 16 + (lane & 15);
    const int tw0  = t0 + tl0;
    const int tw1  = tw0 + 256;

    const float x2v0 = x2_replica<D>(X + (size_t)tw0 * D, lane);
    const float x2v1 = x2_replica<D>(X + (size_t)tw1 * D, lane);
    if ((lane >> 4) == 0) { x2_save[tw0] = x2v0; x2_save[tw1] = x2v1; }

    bf16x8 bhi0[DS], blo0[DS], bhi1[DS], blo1[DS];
    load_frags(X + (size_t)tw0 * D + ((lane >> 4) & 3) * 8, bhi0, blo0, DS);
    load_frags(X + (size_t)tw1 * D + ((lane >> 4) & 3) * 8, bhi1, blo1, DS);

    float b1v0 = FLT_MAX, b2v0 = FLT_MAX, b1v1 = FLT_MAX, b2v1 = FLT_MAX;
    int   b1i0 = 0, b1i1 = 0;
    {
        const int g = lane >> 4;
        for (int st = 0; st < NST; ++st) {
            __syncthreads();
            const unsigned char* src = Wsp + (size_t)st * SB;
            #pragma unroll
            for (int s = 0; s < ITER; ++s)
                GLOAD16(src + tid * 16 + s * 16384, lds + tid * 16 + s * 16384);
            __syncthreads();
            #pragma unroll
            for (int j = 0; j < CH; ++j) {
                const unsigned char* base = lds + j * (D * 64) + lane * 16;
                f32x4 p0 = {0,0,0,0}, p1 = {0,0,0,0}, p2 = {0,0,0,0};
                f32x4 q0 = {0,0,0,0}, q1 = {0,0,0,0}, q2 = {0,0,0,0};
                #pragma unroll
                for (int ds = 0; ds < DS; ++ds) {
                    bf16x8 ahi = *(const bf16x8*)(base + ds * 1024);
                    bf16x8 alo = *(const bf16x8*)(base + D * 32 + ds * 1024);
                    p0 = __builtin_amdgcn_mfma_f32_16x16x32_bf16(ahi, bhi0[ds], p0, 0, 0, 0);
                    q0 = __builtin_amdgcn_mfma_f32_16x16x32_bf16(ahi, bhi1[ds], q0, 0, 0, 0);
                    p1 = __builtin_amdgcn_mfma_f32_16x16x32_bf16(ahi, blo0[ds], p1, 0, 0, 0);
                    q1 = __builtin_amdgcn_mfma_f32_16x16x32_bf16(ahi, blo1[ds], q1, 0, 0, 0);
                    p2 = __builtin_amdgcn_mfma_f32_16x16x32_bf16(alo, bhi0[ds], p2, 0, 0, 0);
                    q2 = __builtin_amdgcn_mfma_f32_16x16x32_bf16(alo, bhi1[ds], q2, 0, 0, 0);
                }
                const int kb = (st * CH + j) * 16 + g * 4;
                #pragma unroll
                for (int r = 0; r < 4; ++r) {
                    float w2r = w2[kb + r];
                    float d0 = __fadd_rn(__fadd_rn(p0[r], p1[r]), p2[r]);
                    float s0 = fmaf(-2.f, d0, w2r);
                    if (s0 < b1v0)      { b2v0 = b1v0; b1v0 = s0; b1i0 = kb + r; }
                    else if (s0 < b2v0) { b2v0 = s0; }
                    float d1 = __fadd_rn(__fadd_rn(q0[r], q1[r]), q2[r]);
                    float s1 = fmaf(-2.f, d1, w2r);
                    if (s1 < b1v1)      { b2v1 = b1v1; b1v1 = s1; b1i1 = kb + r; }
                    else if (s1 < b2v1) { b2v1 = s1; }
                }
            }
        }
    }

    float ls = merge_flag(b1v0, b2v0, b1i0, x2v0, tw0, tl0, lane,
                          idx_s, idx_out, cnt_m, lst_m)
             + merge_flag(b1v1, b2v1, b1i1, x2v1, tw1, tl0 + 256, lane,
                          idx_s, idx_out, cnt_m, lst_m);
    #pragma unroll
    for (int off = 32; off > 0; off >>= 1) ls += __shfl_down(ls, off, 64);
    if (lane == 0) lred[wv] = ls;
    __syncthreads();
    if (tid == 0) {
        float tot = 0.f;
        #pragma unroll
        for (int r = 0; r < 16; ++r) tot += lred[r];
        atomicAdd(P.loss, tot * inv_nd);
    }

    for (int i = tid; i < 512 * (D / 4); i += 1024) {
        int d4 = i % (D / 4);
        int t  = i / (D / 4);
        int k  = idx_s[t];
        const float4 w = *(const float4*)(W + (size_t)k * D + d4 * 4);
        *(float4*)(q_out + (size_t)(t0 + t) * D + d4 * 4) = w;
    }
}

__global__ __launch_bounds__(1024) void vq_mega(AllPtrs P) {
    __shared__ __align__(16) unsigned char lds[65536];
    __shared__ int   idx_s[512];
    __shared__ float lred[16];
    const int bid = blockIdx.x;
    if (bid < 128)       vq_body <256, 512, 4, 0>(P, bid,       lds, idx_s, lred);
    else if (bid < 192)  vq_body2<128, 256, 8, 1>(P, bid - 128, lds, idx_s, lred);
    else if (bid < 256)  vq_body2<128, 256, 8, 3>(P, bid - 192, lds, idx_s, lred);
    else if (bid < 320)  vq_body2<64,  128, 8, 2>(P, bid - 256, lds, idx_s, lred);
    else                 vq_body2<64,  128, 8, 4>(P, bid - 320, lds, idx_s, lred);
}

// ---- unified cleanup: f32 prescan -> tiny f64 np-replica rescore -> patch --
template <int D, int K, int M>
__device__ void cleanup_body(const AllPtrs& P, int sbid, int sblk,
                             float* s32s, int* cand, float* rdv, int* rdi,
                             int* sh, float* wmin)
{
    constexpr int EPL = D / 16;
    const float* X  = P.X[M];
    const float* W  = P.W[M];
    const float* w2 = P.w2[M];
    const float* x2 = P.x2[M];
    const int* list = P.lst + M * NTOK;
    float* q_out   = P.q[M];
    float* idx_out = P.idx[M];
    const float inv_nd = 1.0f / (32768.0f * (float)D);
    const int n   = P.cnt[M];
    const int tid = threadIdx.x;
    const int cg  = tid >> 4;
    const int sub = tid & 15;

    for (int e = sbid; e < n; e += sblk) {
        __syncthreads();
        const int t = list[e];
        const float x2t = x2[t];
        const float* xp = X + (size_t)t * D + sub * EPL;
        float xr[EPL];
        for (int j = 0; j < EPL / 4; ++j) {
            float4 v = *(const float4*)(xp + j * 4);
            xr[j * 4 + 0] = v.x; xr[j * 4 + 1] = v.y;
            xr[j * 4 + 2] = v.z; xr[j * 4 + 3] = v.w;
        }
        if (tid == 0) sh[0] = 0;
        for (int it = 0; it < K / 16; ++it) {
            const int k = it * 16 + cg;
            const float* wp = W + (size_t)k * D + sub * EPL;
            float a = 0.f;
            for (int j = 0; j < EPL / 4; ++j) {
                float4 wv = *(const float4*)(wp + j * 4);
                a = fmaf(xr[j * 4 + 0], wv.x, a);
                a = fmaf(xr[j * 4 + 1], wv.y, a);
                a = fmaf(xr[j * 4 + 2], wv.z, a);
                a = fmaf(xr[j * 4 + 3], wv.w, a);
            }
            a += __shfl_down(a, 8, 16);
            a += __shfl_down(a, 4, 16);
            a += __shfl_down(a, 2, 16);
            a += __shfl_down(a, 1, 16);
            if (sub == 0) s32s[k] = fmaf(-2.f, a, w2[k]);
        }
        __syncthreads();
        float lm = FLT_MAX;
        for (int k = tid; k < K; k += 256) lm = fminf(lm, s32s[k]);
        #pragma unroll
        for (int off = 32; off; off >>= 1) lm = fminf(lm, __shfl_down(lm, off, 64));
        if ((tid & 63) == 0) wmin[tid >> 6] = lm;
        __syncthreads();
        const float m32 = fminf(fminf(wmin[0], wmin[1]), fminf(wmin[2], wmin[3]));
        const float win = fmaf(x2t, 2.6e-7f, 6e-6f);
        for (int k = tid; k < K; k += 256)
            if (s32s[k] <= m32 + win) {
                int p = atomicAdd(&sh[0], 1);
                if (p < 64) cand[p] = k;
            }
        __syncthreads();
        const int nc = sh[0];
        float bd = FLT_MAX; int bk = 0x7fffffff;
        for (int ci = cg; ci < ((nc <= 64) ? nc : K); ci += 16) {
            const int k = (nc <= 64) ? cand[ci] : ci;
            const float* wp = W + (size_t)k * D + sub * EPL;
            double a = 0.0;
            for (int j = 0; j < EPL; ++j)
                a = fma((double)xr[j], (double)wp[j], a);
            a += __shfl_down(a, 8, 16);
            a += __shfl_down(a, 4, 16);
            a += __shfl_down(a, 2, 16);
            a += __shfl_down(a, 1, 16);
            if (sub == 0) {
                const float m = (float)a;
                const float d = __fsub_rn(__fadd_rn(x2t, w2[k]),
                                          __fmul_rn(2.0f, m));
                if (d < bd || (d == bd && k < bk)) { bd = d; bk = k; }
            }
        }
        if (sub == 0) { rdv[cg] = bd; rdi[cg] = bk; }
        __syncthreads();
        if (tid == 0) {
            float B = rdv[0]; int BI = rdi[0];
            #pragma unroll
            for (int r = 1; r < 16; ++r)
                if (rdv[r] < B || (rdv[r] == B && rdi[r] < BI)) { B = rdv[r]; BI = rdi[r]; }
            const int oldk = (int)idx_out[t];
            sh[1] = BI; sh[2] = oldk;
            if (BI != oldk) idx_out[t] = (float)BI;
        }
        __syncthreads();
        const int nk = sh[1], ok = sh[2];
        if (nk != ok) {
            const float* xq = X + (size_t)t * D;
            const float* wn = W + (size_t)nk * D;
            const float* wo = W + (size_t)ok * D;
            float dl = 0.f;
            for (int d = tid; d < D; d += 256) {
                float xv = xq[d], a = wn[d], b = wo[d];
                q_out[(size_t)t * D + d] = a;
                float da = a - xv, db = b - xv;
                dl = fmaf(da, da, dl);
                dl = fmaf(-db, db, dl);
            }
            #pragma unroll
            for (int off = 32; off; off >>= 1) dl += __shfl_down(dl, off, 64);
            if ((tid & 63) == 0 && dl != 0.f) atomicAdd(P.loss, dl * inv_nd);
        }
    }
}

__global__ __launch_bounds__(256) void cleanup_mega(AllPtrs P) {
    __shared__ float s32s[512];
    __shared__ int   cand[64];
    __shared__ float rdv[16];
    __shared__ int   rdi[16];
    __shared__ int   sh[4];
    __shared__ float wmin[4];
    const int bid = blockIdx.x;
    if (bid < 256)       cleanup_body<256, 512, 0>(P, bid,        256, s32s, cand, rdv, rdi, sh, wmin);
    else if (bid < 512)  cleanup_body<128, 256, 1>(P, bid - 256,  256, s32s, cand, rdv, rdi, sh, wmin);
    else if (bid < 768)  cleanup_body<128, 256, 3>(P, bid - 512,  256, s32s, cand, rdv, rdi, sh, wmin);
    else if (bid < 1024) cleanup_body<64,  128, 2>(P, bid - 768,  256, s32s, cand, rdv, rdi, sh, wmin);
    else                 cleanup_body<64,  128, 4>(P, bid - 1024, 256, s32s, cand, rdv, rdi, sh, wmin);
}

extern "C" void kernel_launch(void* const* d_in, const int* in_sizes, int n_in,
                              void* d_out, int out_size, void* d_ws, size_t ws_size,
                              hipStream_t stream)
{
    float* out = (float*)d_out;
    unsigned char* wsb = (unsigned char*)d_ws;
    float* w2b = (float*)(wsb + WSB_W2);

    AllPtrs P;
    P.X[0] = (const float*)d_in[0]; P.W[0] = (const float*)d_in[1];
    P.X[1] = (const float*)d_in[2]; P.W[1] = (const float*)d_in[3];
    P.X[2] = (const float*)d_in[4]; P.W[2] = (const float*)d_in[5];
    P.X[3] = (const float*)d_in[6]; P.W[3] = (const float*)d_in[7];
    P.X[4] = (const float*)d_in[8]; P.W[4] = (const float*)d_in[9];

    P.q[0] = out;            P.q[1] = out + 8388608;  P.q[2] = out + 12582912;
    P.q[3] = out + 14680064; P.q[4] = out + 18874368;
    P.idx[0] = out + 20971520; P.idx[1] = out + 21004288;
    P.idx[2] = out + 21037056; P.idx[3] = out + 21069824;
    P.idx[4] = out + 21102592;
    P.loss = out + 21135360;

    P.w2[0] = w2b;       P.w2[1] = w2b + 512; P.w2[2] = w2b + 768;
    P.w2[3] = w2b + 896; P.w2[4] = w2b + 1152;
    float* x2b = (float*)(wsb + WSB_X2);
    for (int m = 0; m < 5; ++m) P.x2[m] = x2b + m * NTOK;
    P.cnt  = (int*)(wsb + WSB_CNT);
    P.lst  = (int*)(wsb + WSB_LIST);
    P.Wsp[0] = wsb + WSB_WSP;            // dual-plane: 4*K*D bytes each
    P.Wsp[1] = P.Wsp[0] + 524288;        // 131072
    P.Wsp[2] = P.Wsp[1] + 131072;        // 32768
    P.Wsp[3] = P.Wsp[2] + 32768;         // 131072
    P.Wsp[4] = P.Wsp[3] + 131072;        // 32768

    prep_mega   <<<422,  256,  0, stream>>>(P);
    vq_mega     <<<384,  1024, 0, stream>>>(P);
    cleanup_mega<<<1280, 256,  0, stream>>>(P);
}